// Round 10
// baseline (270.972 us; speedup 1.0000x reference)
//
#include <hip/hip_runtime.h>
#include <math.h>

#define BGR 64          // graphs
#define N0 512          // nodes/graph at level 1
#define E_TOT (BGR*N0*16)
#define EPG 8192        // edge slots per graph, fixed across levels
#define EIT 16          // EPG / 512 threads
#define HID 128
#define SW 16           // feature slice width (8 slices)

// ---- XCD heuristic: blockIdx % 8 -> XCD; graph g pinned to XCD g/8.

// Per-graph level-1 topology: edge copy + degree (LDS atomics) + scan + dinv
// + CSR fill (edges register-buffered). Also zeroes z.
__global__ __launch_bounds__(512) void k_topo0(
    const int* __restrict__ s0, const int* __restrict__ d0,
    int2* __restrict__ edges, int* __restrict__ cnt, int* __restrict__ rowptr,
    float* __restrict__ dinv, int2* __restrict__ csr, float* __restrict__ z){
  __shared__ int   deg[512];
  __shared__ int   sb[512];
  __shared__ int   cur[512];
  __shared__ float dl[512];
  int g = (blockIdx.x & 7)*8 + (blockIdx.x >> 3);
  int t = threadIdx.x;
  int gbase = g*N0, ebase = g*EPG;
  deg[t] = 0;
  if (t < 256) z[g*256 + t] = 0.f;
  __syncthreads();
  int2 ebuf[EIT];
  #pragma unroll
  for (int it = 0; it < EIT; it++){
    int i = ebase + it*512 + t;
    int2 e = make_int2(s0[i], d0[i]);
    ebuf[it] = e;
    edges[i] = e;
    atomicAdd(&deg[e.y - gbase], 1);
  }
  __syncthreads();
  int vdeg = deg[t];
  sb[t] = vdeg; __syncthreads();
  for (int off = 1; off < 512; off <<= 1){
    int add = (t >= off) ? sb[t-off] : 0;
    __syncthreads(); sb[t] += add; __syncthreads();
  }
  int excl = sb[t] - vdeg;
  rowptr[gbase + t] = ebase + excl;
  cnt[gbase + t] = vdeg;
  cur[t] = excl;
  float dv = rsqrtf((float)vdeg + 1.f);
  dl[t] = dv;
  dinv[gbase + t] = dv;
  __syncthreads();
  #pragma unroll
  for (int it = 0; it < EIT; it++){
    int2 e = ebuf[it];
    int sl = e.x - gbase, dc = e.y - gbase;
    int pos = atomicAdd(&cur[dc], 1);
    csr[ebase + pos] = make_int2(e.x, __float_as_int(dl[sl]*dl[dc]));
  }
}

// Shared phase-B gather: 8 lanes per node, float2 per lane (16 feats).
// CSR entries fetched 8-at-a-time by the lane group, broadcast via shfl(w=8).
__device__ __forceinline__ void gather_slice(
    const float* hl, const int2* __restrict__ csr,
    const int* __restrict__ rowptr, const int* __restrict__ cnt,
    const float* __restrict__ dinv, const float* __restrict__ bia,
    const float* __restrict__ Wp, float* __restrict__ gout,
    float* __restrict__ hp_part, int gbase, int nper, int slice,
    int l, int grp){
  const float2* hl2 = (const float2*)hl;
  float2 bb = ((const float2*)bia)[slice*8 + l];
  float2 wp = ((const float2*)Wp)[slice*8 + l];
  for (int nl = grp; nl < nper; nl += 64){
    int node = gbase + nl;
    int start = rowptr[node], c = cnt[node];
    float ax = 0.f, ay = 0.f;
    for (int jb = 0; jb < c; jb += 8){
      int2 e = make_int2(0, 0);
      if (jb + l < c) e = csr[start + jb + l];
      int nb = c - jb; if (nb > 8) nb = 8;
      for (int j = 0; j < nb; j++){
        int   sx  = __shfl(e.x, j, 8);
        float wgt = __int_as_float(__shfl(e.y, j, 8));
        float2 hv = hl2[(sx - gbase)*8 + l];
        ax += wgt*hv.x; ay += wgt*hv.y;
      }
    }
    float di = dinv[node], dd = di*di;
    float2 hs = hl2[nl*8 + l];
    float2 v;
    v.x = fmaxf(ax + hs.x*dd + bb.x, 0.f);
    v.y = fmaxf(ay + hs.y*dd + bb.y, 0.f);
    ((float2*)gout)[node*64 + slice*8 + l] = v;
    float contrib = v.x*wp.x + v.y*wp.y;
    contrib += __shfl_down(contrib, 4, 8);
    contrib += __shfl_down(contrib, 2, 8);
    contrib += __shfl_down(contrib, 1, 8);
    if (l == 0) hp_part[slice*32768 + node] = contrib;
  }
}

// Level-1 fused GEMM+gather: block = (graph, 16-feat slice). grid = 512.
// 512x16 h-slice in LDS (32 KB dynamic) from x (fin=10), gather from LDS.
__global__ __launch_bounds__(512) void k_l1_fused(
    const float* __restrict__ x, const float* __restrict__ W1,
    const int2* __restrict__ csr, const int* __restrict__ rowptr,
    const int* __restrict__ cnt, const float* __restrict__ dinv,
    const float* __restrict__ b1, const float* __restrict__ Wp,
    float* __restrict__ gout, float* __restrict__ hp_part){
  extern __shared__ float hl[];   // 512 x 16 = 32 KB
  int b = blockIdx.x;
  int xcd = b & 7, idx = b >> 3;
  int graph = xcd*8 + (idx >> 3);
  int slice = idx & 7;
  int t = threadIdx.x;
  int gbase = graph*N0;
  // phase A: 32 groups of 16 lanes, 16 nodes each
  int fp = t & 15, gi = t >> 4;
  int f = slice*SW + fp;
  float wcol[10];
  #pragma unroll
  for (int k = 0; k < 10; k++) wcol[k] = W1[k*HID + f];
  for (int n = gi*16; n < gi*16 + 16; n++){
    const float* xr = x + (gbase + n)*10;
    float acc = 0.f;
    #pragma unroll
    for (int k = 0; k < 10; k++) acc += xr[k]*wcol[k];
    hl[n*SW + fp] = acc;
  }
  __syncthreads();
  gather_slice(hl, csr, rowptr, cnt, dinv, b1, Wp, gout, hp_part,
               gbase, N0, slice, t & 7, t >> 3);
}

// Levels 2/3 fused GEMM+gather (fin=128): stage W slice (8 KB) in LDS,
// register-blocked GEMM (4 nodes/acc) into nper x 16 LDS h-slice, gather.
// dyn LDS = (2048 + nper*16) floats. grid = 512.
__global__ __launch_bounds__(512) void k_lx_fused(
    const float* __restrict__ x, const float* __restrict__ W,
    const int2* __restrict__ csr, const int* __restrict__ rowptr,
    const int* __restrict__ cnt, const float* __restrict__ dinv,
    const float* __restrict__ bia, const float* __restrict__ Wp,
    float* __restrict__ gout, float* __restrict__ hp_part, int nper){
  extern __shared__ float smem[];
  float* wl = smem;                 // 128 x 16 W slice (8 KB)
  float* hl = smem + 2048;          // nper x 16 h-slice
  int b = blockIdx.x;
  int xcd = b & 7, idx = b >> 3;
  int graph = xcd*8 + (idx >> 3);
  int slice = idx & 7;
  int t = threadIdx.x;
  int gbase = graph*nper;
  int fp = t & 15, gi = t >> 4, f = slice*SW + fp;
  for (int kk = gi; kk < 128; kk += 32) wl[kk*SW + fp] = W[kk*HID + f];
  __syncthreads();
  // phase A: 32 groups x (nper/32) nodes, register-blocked by 4
  int npg = nper >> 5;
  for (int n0 = gi*npg; n0 < (gi+1)*npg; n0 += 4){
    float acc[4] = {0,0,0,0};
    const float4* xr0 = (const float4*)(x + (gbase + n0)*HID);
    for (int kk = 0; kk < 32; kk++){
      float4 xv[4];
      #pragma unroll
      for (int nd = 0; nd < 4; nd++) xv[nd] = xr0[nd*32 + kk];
      float w0 = wl[(kk*4+0)*SW + fp];
      float w1 = wl[(kk*4+1)*SW + fp];
      float w2 = wl[(kk*4+2)*SW + fp];
      float w3 = wl[(kk*4+3)*SW + fp];
      #pragma unroll
      for (int nd = 0; nd < 4; nd++)
        acc[nd] += xv[nd].x*w0 + xv[nd].y*w1 + xv[nd].z*w2 + xv[nd].w*w3;
    }
    #pragma unroll
    for (int nd = 0; nd < 4; nd++) hl[(n0+nd)*SW + fp] = acc[nd];
  }
  __syncthreads();
  gather_slice(hl, csr, rowptr, cnt, dinv, bia, Wp, gout, hp_part,
               gbase, nper, slice, t & 7, t >> 3);
}

// Per-graph mega: score (sum 8 hp slice-partials, 4-batched CSR loads) ->
// hybrid shfl/LDS bitonic top-k -> pooled rows + fused readout -> relabel +
// next topology. Last level: fused readout finalize + MLP + log_softmax.
__global__ __launch_bounds__(512) void k_mega(
    const float4* __restrict__ gout4, const float* __restrict__ hp_part,
    int2* __restrict__ csr, int* __restrict__ rowptr, int* __restrict__ cnt,
    float* __restrict__ dinv, const float* __restrict__ bp,
    int2* __restrict__ edges, float4* __restrict__ xpool4,
    float* __restrict__ z, int nper, int lastlev,
    const float* __restrict__ L1W, const float* __restrict__ L1b,
    const float* __restrict__ L2W, const float* __restrict__ L2b,
    float* __restrict__ out){
  __shared__ float sv[512];
  __shared__ int   si[512];
  __shared__ float hpl[512];
  __shared__ int   map[512];
  __shared__ int   sb[512];
  __shared__ int   cur[256];
  __shared__ float dl[256];
  __shared__ float4 pmx[16][32];
  __shared__ float4 psm[16][32];
  __shared__ float zr[256];
  __shared__ float h1[128];
  __shared__ float h2[64];
  __shared__ float red[2];
  int g = (blockIdx.x & 7)*8 + (blockIdx.x >> 3);
  int t = threadIdx.x;
  int k = nper >> 1;
  int gbase = g*nper, ebase = g*EPG, gb2 = g*k;
  bool act = t < nper;
  if (act){
    int node = gbase + t;
    float s = 0.f;
    #pragma unroll
    for (int q = 0; q < 8; q++) s += hp_part[q*32768 + node];
    hpl[t] = s;
  }
  __syncthreads();
  float v = 0.f; int idx = t;
  if (act){
    int start = rowptr[gbase + t], c = cnt[gbase + t];
    float a = 0.f;
    int j = 0;
    for (; j + 4 <= c; j += 4){
      int2 e0 = csr[start+j],   e1 = csr[start+j+1];
      int2 e2 = csr[start+j+2], e3 = csr[start+j+3];
      a += __int_as_float(e0.y)*hpl[e0.x - gbase]
         + __int_as_float(e1.y)*hpl[e1.x - gbase]
         + __int_as_float(e2.y)*hpl[e2.x - gbase]
         + __int_as_float(e3.y)*hpl[e3.x - gbase];
    }
    for (; j < c; j++){
      int2 e = csr[start + j];
      a += __int_as_float(e.y)*hpl[e.x - gbase];
    }
    float di = dinv[gbase + t];
    v = tanhf(a + hpl[t]*di*di + bp[0]);
  }
  for (int kk = 2; kk <= nper; kk <<= 1){
    for (int jj = kk >> 1; jj > 0; jj >>= 1){
      if (jj >= 64){
        if (act){ sv[t] = v; si[t] = idx; }
        __syncthreads();
        if (act){
          int p = t ^ jj;
          float pv = sv[p]; int pi = si[p];
          bool amLower = (t & jj) == 0;
          bool dirDesc = (t & kk) == 0;
          bool betterMine = (v > pv) || (v == pv && idx < pi);
          if ((amLower == dirDesc) != betterMine){ v = pv; idx = pi; }
        }
        __syncthreads();
      } else if (act){
        float pv = __shfl_xor(v, jj);
        int   pi = __shfl_xor(idx, jj);
        bool amLower = (t & jj) == 0;
        bool dirDesc = (t & kk) == 0;
        bool betterMine = (v > pv) || (v == pv && idx < pi);
        if ((amLower == dirDesc) != betterMine){ v = pv; idx = pi; }
      }
    }
  }
  if (act){ sv[t] = v; si[t] = idx; }
  __syncthreads();
  int l = t & 31, j0 = t >> 5;
  float4 mx = make_float4(-INFINITY,-INFINITY,-INFINITY,-INFINITY);
  float4 sm = make_float4(0.f,0.f,0.f,0.f);
  for (int j = j0; j < k; j += 16){
    float val = sv[j]; int row = si[j];
    float4 hv = gout4[(gbase + row)*32 + l];
    float4 o = make_float4(hv.x*val, hv.y*val, hv.z*val, hv.w*val);
    if (!lastlev) xpool4[(gb2 + j)*32 + l] = o;
    mx.x = fmaxf(mx.x, o.x); mx.y = fmaxf(mx.y, o.y);
    mx.z = fmaxf(mx.z, o.z); mx.w = fmaxf(mx.w, o.w);
    sm.x += o.x; sm.y += o.y; sm.z += o.z; sm.w += o.w;
  }
  pmx[j0][l] = mx; psm[j0][l] = sm;
  __syncthreads();
  if (t < 32){
    float4 M = pmx[0][t], S = psm[0][t];
    #pragma unroll
    for (int q = 1; q < 16; q++){
      float4 m2 = pmx[q][t], s2 = psm[q][t];
      M.x = fmaxf(M.x, m2.x); M.y = fmaxf(M.y, m2.y);
      M.z = fmaxf(M.z, m2.z); M.w = fmaxf(M.w, m2.w);
      S.x += s2.x; S.y += s2.y; S.z += s2.z; S.w += s2.w;
    }
    float ki = 1.f/(float)k;
    float* zp = z + g*256;
    if (!lastlev){
      zp[t*4+0] += M.x; zp[t*4+1] += M.y; zp[t*4+2] += M.z; zp[t*4+3] += M.w;
      zp[128+t*4+0] += S.x*ki; zp[128+t*4+1] += S.y*ki;
      zp[128+t*4+2] += S.z*ki; zp[128+t*4+3] += S.w*ki;
    } else {
      zr[t*4+0] = zp[t*4+0] + M.x; zr[t*4+1] = zp[t*4+1] + M.y;
      zr[t*4+2] = zp[t*4+2] + M.z; zr[t*4+3] = zp[t*4+3] + M.w;
      zr[128+t*4+0] = zp[128+t*4+0] + S.x*ki;
      zr[128+t*4+1] = zp[128+t*4+1] + S.y*ki;
      zr[128+t*4+2] = zp[128+t*4+2] + S.z*ki;
      zr[128+t*4+3] = zp[128+t*4+3] + S.w*ki;
    }
  }
  if (lastlev){
    __syncthreads();
    if (t < 128){
      float a = L1b[t];
      for (int i = 0; i < 256; i++) a += zr[i]*L1W[i*128 + t];
      h1[t] = fmaxf(a, 0.f);
    }
    __syncthreads();
    if (t < 64){
      float a = L2b[t];
      for (int i = 0; i < 128; i++) a += h1[i]*L2W[i*64 + t];
      h2[t] = fmaxf(a, 0.f);
    }
    __syncthreads();
    if (t == 0){
      float mxv = -INFINITY;
      for (int i = 0; i < 64; i++) mxv = fmaxf(mxv, h2[i]);
      float s = 0.f;
      for (int i = 0; i < 64; i++) s += expf(h2[i] - mxv);
      red[0] = mxv; red[1] = logf(s);
    }
    __syncthreads();
    if (t < 64) out[g*64 + t] = h2[t] - red[0] - red[1];
    return;
  }
  if (act) map[t] = -1;
  if (t < k) sb[t] = 0;
  __syncthreads();
  if (t < k) map[si[t]] = t;
  __syncthreads();
  int2 ebuf[EIT];
  #pragma unroll
  for (int it = 0; it < EIT; it++){
    int i = ebase + it*512 + t;
    int2 e = edges[i];
    int2 ne = make_int2(-1, 0);
    if (e.x >= 0){
      int ns = map[e.x - gbase], nd = map[e.y - gbase];
      if (ns >= 0 && nd >= 0){
        ne = make_int2(gb2 + ns, gb2 + nd);
        atomicAdd(&sb[nd], 1);
      }
    }
    ebuf[it] = ne;
    edges[i] = ne;
  }
  __syncthreads();
  int vdeg = (t < k) ? sb[t] : 0;
  for (int off = 1; off < k; off <<= 1){
    int add = (t >= off && t < k) ? sb[t-off] : 0;
    __syncthreads();
    if (t < k) sb[t] += add;
    __syncthreads();
  }
  if (t < k){
    int excl = sb[t] - vdeg;
    rowptr[gb2 + t] = ebase + excl;
    cnt[gb2 + t] = vdeg;
    cur[t] = excl;
    float dv = rsqrtf((float)vdeg + 1.f);
    dl[t] = dv;
    dinv[gb2 + t] = dv;
  }
  __syncthreads();
  #pragma unroll
  for (int it = 0; it < EIT; it++){
    int2 e = ebuf[it];
    if (e.x >= 0){
      int sl = e.x - gb2, dc = e.y - gb2;
      int pos = atomicAdd(&cur[dc], 1);
      csr[ebase + pos] = make_int2(e.x, __float_as_int(dl[sl]*dl[dc]));
    }
  }
}

extern "C" void kernel_launch(void* const* d_in, const int* in_sizes, int n_in,
                              void* d_out, int out_size, void* d_ws, size_t ws_size,
                              hipStream_t stream){
  (void)in_sizes; (void)n_in; (void)out_size; (void)ws_size;
  const float* x0  = (const float*)d_in[0];
  const int*   s0  = (const int*)  d_in[1];
  const int*   d0  = (const int*)  d_in[2];
  const float* W1  = (const float*)d_in[3];  const float* b1 = (const float*)d_in[4];
  const float* W2  = (const float*)d_in[5];  const float* b2 = (const float*)d_in[6];
  const float* W3  = (const float*)d_in[7];  const float* b3 = (const float*)d_in[8];
  const float* Wp  = (const float*)d_in[9];  const float* bp = (const float*)d_in[10];
  const float* L1W = (const float*)d_in[11]; const float* L1b = (const float*)d_in[12];
  const float* L2W = (const float*)d_in[13]; const float* L2b = (const float*)d_in[14];
  float* out = (float*)d_out;

  float* w = (float*)d_ws;
  float* gout  = w; w += 32768*HID;
  float* xpA   = w; w += 16384*HID;          // level-1 pool out
  float* xpB   = w; w += 8192*HID;           // level-2 pool out
  float* dinvv = w; w += 32768;
  float* hppt  = w; w += 8*32768;            // hp slice-partials (8 slices)
  float* z     = w; w += BGR*256;
  int* cnt     = (int*)w; w += 32768;
  int* rowptr  = (int*)w; w += 32768;
  int2* edges  = (int2*)w; w += 2*E_TOT;
  int2* csr    = (int2*)w; w += 2*E_TOT;

  k_topo0<<<BGR, 512, 0, stream>>>(s0, d0, edges, cnt, rowptr, dinvv, csr, z);

  // level 1: 512 -> 256
  k_l1_fused<<<512, 512, N0*SW*4, stream>>>(x0, W1, csr, rowptr, cnt, dinvv,
                                            b1, Wp, gout, hppt);
  k_mega<<<BGR, 512, 0, stream>>>((const float4*)gout, hppt, csr, rowptr, cnt,
                                  dinvv, bp, edges, (float4*)xpA, z, 512, 0,
                                  L1W, L1b, L2W, L2b, out);
  // level 2: 256 -> 128
  k_lx_fused<<<512, 512, (2048 + 256*SW)*4, stream>>>(xpA, W2, csr, rowptr, cnt,
                                                      dinvv, b2, Wp, gout,
                                                      hppt, 256);
  k_mega<<<BGR, 512, 0, stream>>>((const float4*)gout, hppt, csr, rowptr, cnt,
                                  dinvv, bp, edges, (float4*)xpB, z, 256, 0,
                                  L1W, L1b, L2W, L2b, out);
  // level 3: 128 -> 64 (+ fused readout/MLP/log_softmax)
  k_lx_fused<<<512, 512, (2048 + 128*SW)*4, stream>>>(xpB, W3, csr, rowptr, cnt,
                                                      dinvv, b3, Wp, gout,
                                                      hppt, 128);
  k_mega<<<BGR, 512, 0, stream>>>((const float4*)gout, hppt, csr, rowptr, cnt,
                                  dinvv, bp, edges, (float4*)xpA, z, 128, 1,
                                  L1W, L1b, L2W, L2b, out);
}

// Round 11
// 248.358 us; speedup vs baseline: 1.0911x; 1.0911x over previous
//
#include <hip/hip_runtime.h>
#include <math.h>

#define BGR 64          // graphs
#define N0 512          // nodes/graph at level 1
#define E_TOT (BGR*N0*16)
#define EPG 8192        // edge slots per graph, fixed across levels
#define EIT 16          // EPG / 512 threads
#define HID 128

// ---- XCD heuristic: blockIdx % 8 -> XCD; graph g pinned to XCD g/8.

// Per-graph level-1 topology: edge copy + degree (LDS atomics) + scan + dinv
// + CSR fill (edges register-buffered). Also zeroes z.
__global__ __launch_bounds__(512) void k_topo0(
    const int* __restrict__ s0, const int* __restrict__ d0,
    int2* __restrict__ edges, int* __restrict__ cnt, int* __restrict__ rowptr,
    float* __restrict__ dinv, int2* __restrict__ csr, float* __restrict__ z){
  __shared__ int   deg[512];
  __shared__ int   sb[512];
  __shared__ int   cur[512];
  __shared__ float dl[512];
  int g = (blockIdx.x & 7)*8 + (blockIdx.x >> 3);
  int t = threadIdx.x;
  int gbase = g*N0, ebase = g*EPG;
  deg[t] = 0;
  if (t < 256) z[g*256 + t] = 0.f;
  __syncthreads();
  int2 ebuf[EIT];
  #pragma unroll
  for (int it = 0; it < EIT; it++){
    int i = ebase + it*512 + t;
    int2 e = make_int2(s0[i], d0[i]);
    ebuf[it] = e;
    edges[i] = e;
    atomicAdd(&deg[e.y - gbase], 1);
  }
  __syncthreads();
  int vdeg = deg[t];
  sb[t] = vdeg; __syncthreads();
  for (int off = 1; off < 512; off <<= 1){
    int add = (t >= off) ? sb[t-off] : 0;
    __syncthreads(); sb[t] += add; __syncthreads();
  }
  int excl = sb[t] - vdeg;
  rowptr[gbase + t] = ebase + excl;
  cnt[gbase + t] = vdeg;
  cur[t] = excl;
  float dv = rsqrtf((float)vdeg + 1.f);
  dl[t] = dv;
  dinv[gbase + t] = dv;
  __syncthreads();
  #pragma unroll
  for (int it = 0; it < EIT; it++){
    int2 e = ebuf[it];
    int sl = e.x - gbase, dc = e.y - gbase;
    int pos = atomicAdd(&cur[dc], 1);
    csr[ebase + pos] = make_int2(e.x, __float_as_int(dl[sl]*dl[dc]));
  }
}

// Level-1 fused GEMM+gather: block = (graph, feature-quarter). Computes the
// 512x32 h-slice in LDS (64 KB dynamic) from x (fin=10), then gathers
// neighbors from LDS with 4-batched CSR loads. Writes gout quarter + hp part.
__global__ __launch_bounds__(512) void k_l1_fused(
    const float* __restrict__ x, const float* __restrict__ W1,
    const int2* __restrict__ csr, const int* __restrict__ rowptr,
    const int* __restrict__ cnt, const float* __restrict__ dinv,
    const float* __restrict__ b1, const float* __restrict__ Wp,
    float4* __restrict__ gout4, float* __restrict__ hp_part){
  extern __shared__ float hl[];   // 512 nodes x 32 feats = 64 KB
  int b = blockIdx.x;
  int xcd = b & 7, idx = b >> 3;
  int graph = xcd*8 + (idx >> 2);
  int qf = idx & 3;
  int t = threadIdx.x;
  int gbase = graph*N0;
  int fp = t & 31;
  int f = qf*32 + fp;
  float wcol[10];
  #pragma unroll
  for (int k = 0; k < 10; k++) wcol[k] = W1[k*HID + f];
  for (int n = t >> 5; n < N0; n += 16){
    const float* xr = x + (gbase + n)*10;
    float acc = 0.f;
    #pragma unroll
    for (int k = 0; k < 10; k++) acc += xr[k]*wcol[k];
    hl[n*32 + fp] = acc;
  }
  __syncthreads();
  const float4* hl4 = (const float4*)hl;
  int l = t & 7, grp = t >> 3;
  float4 bb = ((const float4*)b1)[qf*8 + l];
  float4 wp = ((const float4*)Wp)[qf*8 + l];
  for (int nl = grp; nl < N0; nl += 64){
    int node = gbase + nl;
    int start = rowptr[node], c = cnt[node];
    float4 acc = make_float4(0.f,0.f,0.f,0.f);
    int j = 0;
    for (; j + 4 <= c; j += 4){
      int2 e0 = csr[start+j],   e1 = csr[start+j+1];
      int2 e2 = csr[start+j+2], e3 = csr[start+j+3];
      float4 h0 = hl4[(e0.x - gbase)*8 + l];
      float4 h1 = hl4[(e1.x - gbase)*8 + l];
      float4 h2 = hl4[(e2.x - gbase)*8 + l];
      float4 h3 = hl4[(e3.x - gbase)*8 + l];
      float w0 = __int_as_float(e0.y), w1 = __int_as_float(e1.y);
      float w2 = __int_as_float(e2.y), w3 = __int_as_float(e3.y);
      acc.x += w0*h0.x + w1*h1.x + w2*h2.x + w3*h3.x;
      acc.y += w0*h0.y + w1*h1.y + w2*h2.y + w3*h3.y;
      acc.z += w0*h0.z + w1*h1.z + w2*h2.z + w3*h3.z;
      acc.w += w0*h0.w + w1*h1.w + w2*h2.w + w3*h3.w;
    }
    for (; j < c; j++){
      int2 e = csr[start + j];
      float wgt = __int_as_float(e.y);
      float4 hv = hl4[(e.x - gbase)*8 + l];
      acc.x += wgt*hv.x; acc.y += wgt*hv.y; acc.z += wgt*hv.z; acc.w += wgt*hv.w;
    }
    float di = dinv[node], dd = di*di;
    float4 hs = hl4[nl*8 + l];
    float4 v;
    v.x = fmaxf(acc.x + hs.x*dd + bb.x, 0.f);
    v.y = fmaxf(acc.y + hs.y*dd + bb.y, 0.f);
    v.z = fmaxf(acc.z + hs.z*dd + bb.z, 0.f);
    v.w = fmaxf(acc.w + hs.w*dd + bb.w, 0.f);
    gout4[node*32 + qf*8 + l] = v;
    float contrib = v.x*wp.x + v.y*wp.y + v.z*wp.z + v.w*wp.w;
    #pragma unroll
    for (int off = 4; off; off >>= 1) contrib += __shfl_down(contrib, off, 8);
    if (l == 0) hp_part[qf*32768 + node] = contrib;
  }
}

// h = x @ W (fin=128), 16 nodes per 128-thread block, XCD-pinned.
__global__ void k_gemm16(const float* __restrict__ x, const float* __restrict__ W,
                         float* __restrict__ out, int nper){
  __shared__ float xr[16][HID];
  int b = blockIdx.x;
  int xcd = b & 7, idx = b >> 3, bpg = nper >> 4;
  int graph = xcd*8 + idx / bpg;
  int base = graph*nper + (idx % bpg)*16;
  int f = threadIdx.x;
  #pragma unroll
  for (int nd = 0; nd < 16; nd++) xr[nd][f] = x[(base+nd)*HID + f];
  __syncthreads();
  float acc[16];
  #pragma unroll
  for (int nd = 0; nd < 16; nd++) acc[nd] = 0.f;
  for (int i = 0; i < HID; i++){
    float wv = W[i*HID + f];
    #pragma unroll
    for (int nd = 0; nd < 16; nd++) acc[nd] += xr[nd][i]*wv;
  }
  #pragma unroll
  for (int nd = 0; nd < 16; nd++) out[(base+nd)*HID + f] = acc[nd];
}

// gather GCN (levels 2/3), float4: 32 lanes per node-row, 8 nodes per block,
// 4-batched CSR loads. XCD-pinned.
__global__ __launch_bounds__(256) void k_gcn_gather(
    const float4* __restrict__ h4, const int2* __restrict__ csr,
    const int* __restrict__ rowptr, const int* __restrict__ cnt,
    const float* __restrict__ dinv, const float4* __restrict__ bias4,
    const float4* __restrict__ Wp4, float4* __restrict__ out4,
    float* __restrict__ hp, int nper){
  int b = blockIdx.x;
  int xcd = b & 7, idx = b >> 3, bpg = nper >> 3;
  int graph = xcd*8 + idx / bpg;
  int node = graph*nper + (idx % bpg)*8 + (threadIdx.x >> 5);
  int l = threadIdx.x & 31;
  int start = rowptr[node], c = cnt[node];
  float4 acc = make_float4(0.f, 0.f, 0.f, 0.f);
  int j = 0;
  for (; j + 4 <= c; j += 4){
    int2 e0 = csr[start+j],   e1 = csr[start+j+1];
    int2 e2 = csr[start+j+2], e3 = csr[start+j+3];
    float4 h0 = h4[e0.x*32 + l];
    float4 h1 = h4[e1.x*32 + l];
    float4 h2 = h4[e2.x*32 + l];
    float4 h3 = h4[e3.x*32 + l];
    float w0 = __int_as_float(e0.y), w1 = __int_as_float(e1.y);
    float w2 = __int_as_float(e2.y), w3 = __int_as_float(e3.y);
    acc.x += w0*h0.x + w1*h1.x + w2*h2.x + w3*h3.x;
    acc.y += w0*h0.y + w1*h1.y + w2*h2.y + w3*h3.y;
    acc.z += w0*h0.z + w1*h1.z + w2*h2.z + w3*h3.z;
    acc.w += w0*h0.w + w1*h1.w + w2*h2.w + w3*h3.w;
  }
  for (; j < c; j++){
    int2 e = csr[start + j];
    float wgt = __int_as_float(e.y);
    float4 hv = h4[e.x*32 + l];
    acc.x += wgt*hv.x; acc.y += wgt*hv.y; acc.z += wgt*hv.z; acc.w += wgt*hv.w;
  }
  float di = dinv[node], dd = di*di;
  float4 hs = h4[node*32 + l];
  float4 bb = bias4[l];
  float4 v;
  v.x = fmaxf(acc.x + hs.x*dd + bb.x, 0.f);
  v.y = fmaxf(acc.y + hs.y*dd + bb.y, 0.f);
  v.z = fmaxf(acc.z + hs.z*dd + bb.z, 0.f);
  v.w = fmaxf(acc.w + hs.w*dd + bb.w, 0.f);
  out4[node*32 + l] = v;
  float4 wp = Wp4[l];
  float contrib = v.x*wp.x + v.y*wp.y + v.z*wp.z + v.w*wp.w;
  #pragma unroll
  for (int off = 16; off; off >>= 1) contrib += __shfl_down(contrib, off, 32);
  if (l == 0) hp[node] = contrib;
}

// Per-graph mega: score (4-batched CSR loads) -> hybrid shfl/LDS bitonic
// top-k -> pooled rows + fused readout -> relabel + next topology.
// Last level: fused readout finalize + MLP + log_softmax.
__global__ __launch_bounds__(512) void k_mega(
    const float4* __restrict__ gout4, const float* __restrict__ hp_part,
    int l1flag, const float* __restrict__ hp,
    int2* __restrict__ csr, int* __restrict__ rowptr, int* __restrict__ cnt,
    float* __restrict__ dinv, const float* __restrict__ bp,
    int2* __restrict__ edges, float4* __restrict__ xpool4,
    float* __restrict__ z, int nper, int lastlev,
    const float* __restrict__ L1W, const float* __restrict__ L1b,
    const float* __restrict__ L2W, const float* __restrict__ L2b,
    float* __restrict__ out){
  __shared__ float sv[512];
  __shared__ int   si[512];
  __shared__ float hpl[512];
  __shared__ int   map[512];
  __shared__ int   sb[512];
  __shared__ int   cur[256];
  __shared__ float dl[256];
  __shared__ float4 pmx[16][32];
  __shared__ float4 psm[16][32];
  __shared__ float zr[256];
  __shared__ float h1[128];
  __shared__ float h2[64];
  __shared__ float red[2];
  int g = (blockIdx.x & 7)*8 + (blockIdx.x >> 3);
  int t = threadIdx.x;
  int k = nper >> 1;
  int gbase = g*nper, ebase = g*EPG, gb2 = g*k;
  bool act = t < nper;
  if (act){
    int node = gbase + t;
    hpl[t] = l1flag ? (hp_part[node] + hp_part[32768 + node] +
                       hp_part[65536 + node] + hp_part[98304 + node])
                    : hp[node];
  }
  __syncthreads();
  float v = 0.f; int idx = t;
  if (act){
    int start = rowptr[gbase + t], c = cnt[gbase + t];
    float a = 0.f;
    int j = 0;
    for (; j + 4 <= c; j += 4){
      int2 e0 = csr[start+j],   e1 = csr[start+j+1];
      int2 e2 = csr[start+j+2], e3 = csr[start+j+3];
      a += __int_as_float(e0.y)*hpl[e0.x - gbase]
         + __int_as_float(e1.y)*hpl[e1.x - gbase]
         + __int_as_float(e2.y)*hpl[e2.x - gbase]
         + __int_as_float(e3.y)*hpl[e3.x - gbase];
    }
    for (; j < c; j++){
      int2 e = csr[start + j];
      a += __int_as_float(e.y)*hpl[e.x - gbase];
    }
    float di = dinv[gbase + t];
    v = tanhf(a + hpl[t]*di*di + bp[0]);
  }
  for (int kk = 2; kk <= nper; kk <<= 1){
    for (int jj = kk >> 1; jj > 0; jj >>= 1){
      if (jj >= 64){
        if (act){ sv[t] = v; si[t] = idx; }
        __syncthreads();
        if (act){
          int p = t ^ jj;
          float pv = sv[p]; int pi = si[p];
          bool amLower = (t & jj) == 0;
          bool dirDesc = (t & kk) == 0;
          bool betterMine = (v > pv) || (v == pv && idx < pi);
          if ((amLower == dirDesc) != betterMine){ v = pv; idx = pi; }
        }
        __syncthreads();
      } else if (act){
        float pv = __shfl_xor(v, jj);
        int   pi = __shfl_xor(idx, jj);
        bool amLower = (t & jj) == 0;
        bool dirDesc = (t & kk) == 0;
        bool betterMine = (v > pv) || (v == pv && idx < pi);
        if ((amLower == dirDesc) != betterMine){ v = pv; idx = pi; }
      }
    }
  }
  if (act){ sv[t] = v; si[t] = idx; }
  __syncthreads();
  int l = t & 31, j0 = t >> 5;
  float4 mx = make_float4(-INFINITY,-INFINITY,-INFINITY,-INFINITY);
  float4 sm = make_float4(0.f,0.f,0.f,0.f);
  for (int j = j0; j < k; j += 16){
    float val = sv[j]; int row = si[j];
    float4 hv = gout4[(gbase + row)*32 + l];
    float4 o = make_float4(hv.x*val, hv.y*val, hv.z*val, hv.w*val);
    if (!lastlev) xpool4[(gb2 + j)*32 + l] = o;
    mx.x = fmaxf(mx.x, o.x); mx.y = fmaxf(mx.y, o.y);
    mx.z = fmaxf(mx.z, o.z); mx.w = fmaxf(mx.w, o.w);
    sm.x += o.x; sm.y += o.y; sm.z += o.z; sm.w += o.w;
  }
  pmx[j0][l] = mx; psm[j0][l] = sm;
  __syncthreads();
  if (t < 32){
    float4 M = pmx[0][t], S = psm[0][t];
    #pragma unroll
    for (int q = 1; q < 16; q++){
      float4 m2 = pmx[q][t], s2 = psm[q][t];
      M.x = fmaxf(M.x, m2.x); M.y = fmaxf(M.y, m2.y);
      M.z = fmaxf(M.z, m2.z); M.w = fmaxf(M.w, m2.w);
      S.x += s2.x; S.y += s2.y; S.z += s2.z; S.w += s2.w;
    }
    float ki = 1.f/(float)k;
    float* zp = z + g*256;
    if (!lastlev){
      zp[t*4+0] += M.x; zp[t*4+1] += M.y; zp[t*4+2] += M.z; zp[t*4+3] += M.w;
      zp[128+t*4+0] += S.x*ki; zp[128+t*4+1] += S.y*ki;
      zp[128+t*4+2] += S.z*ki; zp[128+t*4+3] += S.w*ki;
    } else {
      zr[t*4+0] = zp[t*4+0] + M.x; zr[t*4+1] = zp[t*4+1] + M.y;
      zr[t*4+2] = zp[t*4+2] + M.z; zr[t*4+3] = zp[t*4+3] + M.w;
      zr[128+t*4+0] = zp[128+t*4+0] + S.x*ki;
      zr[128+t*4+1] = zp[128+t*4+1] + S.y*ki;
      zr[128+t*4+2] = zp[128+t*4+2] + S.z*ki;
      zr[128+t*4+3] = zp[128+t*4+3] + S.w*ki;
    }
  }
  if (lastlev){
    __syncthreads();
    if (t < 128){
      float a = L1b[t];
      for (int i = 0; i < 256; i++) a += zr[i]*L1W[i*128 + t];
      h1[t] = fmaxf(a, 0.f);
    }
    __syncthreads();
    if (t < 64){
      float a = L2b[t];
      for (int i = 0; i < 128; i++) a += h1[i]*L2W[i*64 + t];
      h2[t] = fmaxf(a, 0.f);
    }
    __syncthreads();
    if (t == 0){
      float mxv = -INFINITY;
      for (int i = 0; i < 64; i++) mxv = fmaxf(mxv, h2[i]);
      float s = 0.f;
      for (int i = 0; i < 64; i++) s += expf(h2[i] - mxv);
      red[0] = mxv; red[1] = logf(s);
    }
    __syncthreads();
    if (t < 64) out[g*64 + t] = h2[t] - red[0] - red[1];
    return;
  }
  if (act) map[t] = -1;
  if (t < k) sb[t] = 0;
  __syncthreads();
  if (t < k) map[si[t]] = t;
  __syncthreads();
  int2 ebuf[EIT];
  #pragma unroll
  for (int it = 0; it < EIT; it++){
    int i = ebase + it*512 + t;
    int2 e = edges[i];
    int2 ne = make_int2(-1, 0);
    if (e.x >= 0){
      int ns = map[e.x - gbase], nd = map[e.y - gbase];
      if (ns >= 0 && nd >= 0){
        ne = make_int2(gb2 + ns, gb2 + nd);
        atomicAdd(&sb[nd], 1);
      }
    }
    ebuf[it] = ne;
    edges[i] = ne;
  }
  __syncthreads();
  int vdeg = (t < k) ? sb[t] : 0;
  for (int off = 1; off < k; off <<= 1){
    int add = (t >= off && t < k) ? sb[t-off] : 0;
    __syncthreads();
    if (t < k) sb[t] += add;
    __syncthreads();
  }
  if (t < k){
    int excl = sb[t] - vdeg;
    rowptr[gb2 + t] = ebase + excl;
    cnt[gb2 + t] = vdeg;
    cur[t] = excl;
    float dv = rsqrtf((float)vdeg + 1.f);
    dl[t] = dv;
    dinv[gb2 + t] = dv;
  }
  __syncthreads();
  #pragma unroll
  for (int it = 0; it < EIT; it++){
    int2 e = ebuf[it];
    if (e.x >= 0){
      int sl = e.x - gb2, dc = e.y - gb2;
      int pos = atomicAdd(&cur[dc], 1);
      csr[ebase + pos] = make_int2(e.x, __float_as_int(dl[sl]*dl[dc]));
    }
  }
}

extern "C" void kernel_launch(void* const* d_in, const int* in_sizes, int n_in,
                              void* d_out, int out_size, void* d_ws, size_t ws_size,
                              hipStream_t stream){
  (void)in_sizes; (void)n_in; (void)out_size; (void)ws_size;
  const float* x0  = (const float*)d_in[0];
  const int*   s0  = (const int*)  d_in[1];
  const int*   d0  = (const int*)  d_in[2];
  const float* W1  = (const float*)d_in[3];  const float* b1 = (const float*)d_in[4];
  const float* W2  = (const float*)d_in[5];  const float* b2 = (const float*)d_in[6];
  const float* W3  = (const float*)d_in[7];  const float* b3 = (const float*)d_in[8];
  const float* Wp  = (const float*)d_in[9];  const float* bp = (const float*)d_in[10];
  const float* L1W = (const float*)d_in[11]; const float* L1b = (const float*)d_in[12];
  const float* L2W = (const float*)d_in[13]; const float* L2b = (const float*)d_in[14];
  float* out = (float*)d_out;

  // workspace layout (elements). xp buffers overlay dead tails of h/gout.
  float* w = (float*)d_ws;
  float* h     = w; w += 32768*HID;          // L2/L3 XW scratch
  float* gout  = w; w += 32768*HID;
  float* xpA   = h    + 16384*HID;           // level-1 pool out — h tail
  float* xpB   = gout + 16384*HID;           // level-2 pool out — gout tail
  float* xpC   = xpA;                        // level-3 pool out — xpA dead by then
  float* dinvv = w; w += 32768;
  float* hp    = w; w += 32768;
  float* hppt  = w; w += 4*32768;            // L1 hp quarter-partials
  float* z     = w; w += BGR*256;
  int* cnt     = (int*)w; w += 32768;
  int* rowptr  = (int*)w; w += 32768;
  int2* edges  = (int2*)w; w += 2*E_TOT;
  int2* csr    = (int2*)w; w += 2*E_TOT;

  k_topo0<<<BGR, 512, 0, stream>>>(s0, d0, edges, cnt, rowptr, dinvv, csr, z);

  // level 1: 512 -> 256 (fused gemm+gather in LDS)
  k_l1_fused<<<256, 512, 65536, stream>>>(x0, W1, csr, rowptr, cnt, dinvv,
                                          b1, Wp, (float4*)gout, hppt);
  k_mega<<<BGR, 512, 0, stream>>>((const float4*)gout, hppt, 1, hp, csr, rowptr,
                                  cnt, dinvv, bp, edges, (float4*)xpA, z, 512, 0,
                                  L1W, L1b, L2W, L2b, out);
  // level 2: 256 -> 128
  k_gemm16<<<16384/16, HID, 0, stream>>>(xpA, W2, h, 256);
  k_gcn_gather<<<16384/8, 256, 0, stream>>>((const float4*)h, csr, rowptr, cnt,
                                            dinvv, (const float4*)b2,
                                            (const float4*)Wp, (float4*)gout,
                                            hp, 256);
  k_mega<<<BGR, 512, 0, stream>>>((const float4*)gout, hppt, 0, hp, csr, rowptr,
                                  cnt, dinvv, bp, edges, (float4*)xpB, z, 256, 0,
                                  L1W, L1b, L2W, L2b, out);
  // level 3: 128 -> 64 (+ fused readout/MLP/log_softmax)
  k_gemm16<<<8192/16, HID, 0, stream>>>(xpB, W3, h, 128);
  k_gcn_gather<<<8192/8, 256, 0, stream>>>((const float4*)h, csr, rowptr, cnt,
                                           dinvv, (const float4*)b3,
                                           (const float4*)Wp, (float4*)gout,
                                           hp, 128);
  k_mega<<<BGR, 512, 0, stream>>>((const float4*)gout, hppt, 0, hp, csr, rowptr,
                                  cnt, dinvv, bp, edges, (float4*)xpC, z, 128, 1,
                                  L1W, L1b, L2W, L2b, out);
}

// Round 12
// 247.955 us; speedup vs baseline: 1.0928x; 1.0016x over previous
//
#include <hip/hip_runtime.h>
#include <math.h>

#define BGR 64          // graphs
#define N0 512          // nodes/graph at level 1
#define E_TOT (BGR*N0*16)
#define EPG 8192        // edge slots per graph, fixed across levels
#define EIT 16          // EPG / 512 threads
#define HID 128

// ---- XCD heuristic: blockIdx % 8 -> XCD; graph g pinned to XCD g/8.

// Per-graph level-1 topology: edge copy + degree (LDS atomics) + scan + dinv
// + CSR fill (edges register-buffered).
__global__ __launch_bounds__(512) void k_topo0(
    const int* __restrict__ s0, const int* __restrict__ d0,
    int2* __restrict__ edges, int* __restrict__ cnt, int* __restrict__ rowptr,
    float* __restrict__ dinv, int2* __restrict__ csr){
  __shared__ int   deg[512];
  __shared__ int   sb[512];
  __shared__ int   cur[512];
  __shared__ float dl[512];
  int g = (blockIdx.x & 7)*8 + (blockIdx.x >> 3);
  int t = threadIdx.x;
  int gbase = g*N0, ebase = g*EPG;
  deg[t] = 0;
  __syncthreads();
  int2 ebuf[EIT];
  #pragma unroll
  for (int it = 0; it < EIT; it++){
    int i = ebase + it*512 + t;
    int2 e = make_int2(s0[i], d0[i]);
    ebuf[it] = e;
    edges[i] = e;
    atomicAdd(&deg[e.y - gbase], 1);
  }
  __syncthreads();
  int vdeg = deg[t];
  sb[t] = vdeg; __syncthreads();
  for (int off = 1; off < 512; off <<= 1){
    int add = (t >= off) ? sb[t-off] : 0;
    __syncthreads(); sb[t] += add; __syncthreads();
  }
  int excl = sb[t] - vdeg;
  rowptr[gbase + t] = ebase + excl;
  cnt[gbase + t] = vdeg;
  cur[t] = excl;
  float dv = rsqrtf((float)vdeg + 1.f);
  dl[t] = dv;
  dinv[gbase + t] = dv;
  __syncthreads();
  #pragma unroll
  for (int it = 0; it < EIT; it++){
    int2 e = ebuf[it];
    int sl = e.x - gbase, dc = e.y - gbase;
    int pos = atomicAdd(&cur[dc], 1);
    csr[ebase + pos] = make_int2(e.x, __float_as_int(dl[sl]*dl[dc]));
  }
}

// Level-1 fused GEMM+gather: block = (graph, feature-quarter, node-half).
// grid = 512 (2 blocks/CU). Both halves compute the full 512x32 h-slice in
// LDS (phase A is trivial); each gathers 256 nodes with 4-batched CSR loads.
__global__ __launch_bounds__(512) void k_l1_fused(
    const float* __restrict__ x, const float* __restrict__ W1,
    const int2* __restrict__ csr, const int* __restrict__ rowptr,
    const int* __restrict__ cnt, const float* __restrict__ dinv,
    const float* __restrict__ b1, const float* __restrict__ Wp,
    float4* __restrict__ gout4, float* __restrict__ hp_part){
  extern __shared__ float hl[];   // 512 nodes x 32 feats = 64 KB
  int b = blockIdx.x;
  int xcd = b & 7, idx = b >> 3;          // idx 0..63
  int graph = xcd*8 + (idx >> 3);
  int sub = idx & 7;
  int qf = sub >> 1, half = sub & 1;
  int t = threadIdx.x;
  int gbase = graph*N0;
  int fp = t & 31;
  int f = qf*32 + fp;
  float wcol[10];
  #pragma unroll
  for (int k = 0; k < 10; k++) wcol[k] = W1[k*HID + f];
  for (int n = t >> 5; n < N0; n += 16){
    const float* xr = x + (gbase + n)*10;
    float acc = 0.f;
    #pragma unroll
    for (int k = 0; k < 10; k++) acc += xr[k]*wcol[k];
    hl[n*32 + fp] = acc;
  }
  __syncthreads();
  const float4* hl4 = (const float4*)hl;
  int l = t & 7, grp = t >> 3;
  float4 bb = ((const float4*)b1)[qf*8 + l];
  float4 wp = ((const float4*)Wp)[qf*8 + l];
  int n0 = half*256;
  for (int nl = n0 + grp; nl < n0 + 256; nl += 64){
    int node = gbase + nl;
    int start = rowptr[node], c = cnt[node];
    float4 acc = make_float4(0.f,0.f,0.f,0.f);
    int j = 0;
    for (; j + 4 <= c; j += 4){
      int2 e0 = csr[start+j],   e1 = csr[start+j+1];
      int2 e2 = csr[start+j+2], e3 = csr[start+j+3];
      float4 h0 = hl4[(e0.x - gbase)*8 + l];
      float4 h1 = hl4[(e1.x - gbase)*8 + l];
      float4 h2 = hl4[(e2.x - gbase)*8 + l];
      float4 h3 = hl4[(e3.x - gbase)*8 + l];
      float w0 = __int_as_float(e0.y), w1 = __int_as_float(e1.y);
      float w2 = __int_as_float(e2.y), w3 = __int_as_float(e3.y);
      acc.x += w0*h0.x + w1*h1.x + w2*h2.x + w3*h3.x;
      acc.y += w0*h0.y + w1*h1.y + w2*h2.y + w3*h3.y;
      acc.z += w0*h0.z + w1*h1.z + w2*h2.z + w3*h3.z;
      acc.w += w0*h0.w + w1*h1.w + w2*h2.w + w3*h3.w;
    }
    for (; j < c; j++){
      int2 e = csr[start + j];
      float wgt = __int_as_float(e.y);
      float4 hv = hl4[(e.x - gbase)*8 + l];
      acc.x += wgt*hv.x; acc.y += wgt*hv.y; acc.z += wgt*hv.z; acc.w += wgt*hv.w;
    }
    float di = dinv[node], dd = di*di;
    float4 hs = hl4[nl*8 + l];
    float4 v;
    v.x = fmaxf(acc.x + hs.x*dd + bb.x, 0.f);
    v.y = fmaxf(acc.y + hs.y*dd + bb.y, 0.f);
    v.z = fmaxf(acc.z + hs.z*dd + bb.z, 0.f);
    v.w = fmaxf(acc.w + hs.w*dd + bb.w, 0.f);
    gout4[node*32 + qf*8 + l] = v;
    float contrib = v.x*wp.x + v.y*wp.y + v.z*wp.z + v.w*wp.w;
    #pragma unroll
    for (int off = 4; off; off >>= 1) contrib += __shfl_down(contrib, off, 8);
    if (l == 0) hp_part[qf*32768 + node] = contrib;
  }
}

// h = x @ W (fin=128), 16 nodes per 128-thread block, XCD-pinned.
__global__ void k_gemm16(const float* __restrict__ x, const float* __restrict__ W,
                         float* __restrict__ out, int nper){
  __shared__ float xr[16][HID];
  int b = blockIdx.x;
  int xcd = b & 7, idx = b >> 3, bpg = nper >> 4;
  int graph = xcd*8 + idx / bpg;
  int base = graph*nper + (idx % bpg)*16;
  int f = threadIdx.x;
  #pragma unroll
  for (int nd = 0; nd < 16; nd++) xr[nd][f] = x[(base+nd)*HID + f];
  __syncthreads();
  float acc[16];
  #pragma unroll
  for (int nd = 0; nd < 16; nd++) acc[nd] = 0.f;
  for (int i = 0; i < HID; i++){
    float wv = W[i*HID + f];
    #pragma unroll
    for (int nd = 0; nd < 16; nd++) acc[nd] += xr[nd][i]*wv;
  }
  #pragma unroll
  for (int nd = 0; nd < 16; nd++) out[(base+nd)*HID + f] = acc[nd];
}

// gather GCN (levels 2/3), float4: 32 lanes per node-row, 8 nodes per block,
// 4-batched CSR loads. XCD-pinned.
__global__ __launch_bounds__(256) void k_gcn_gather(
    const float4* __restrict__ h4, const int2* __restrict__ csr,
    const int* __restrict__ rowptr, const int* __restrict__ cnt,
    const float* __restrict__ dinv, const float4* __restrict__ bias4,
    const float4* __restrict__ Wp4, float4* __restrict__ out4,
    float* __restrict__ hp, int nper){
  int b = blockIdx.x;
  int xcd = b & 7, idx = b >> 3, bpg = nper >> 3;
  int graph = xcd*8 + idx / bpg;
  int node = graph*nper + (idx % bpg)*8 + (threadIdx.x >> 5);
  int l = threadIdx.x & 31;
  int start = rowptr[node], c = cnt[node];
  float4 acc = make_float4(0.f, 0.f, 0.f, 0.f);
  int j = 0;
  for (; j + 4 <= c; j += 4){
    int2 e0 = csr[start+j],   e1 = csr[start+j+1];
    int2 e2 = csr[start+j+2], e3 = csr[start+j+3];
    float4 h0 = h4[e0.x*32 + l];
    float4 h1 = h4[e1.x*32 + l];
    float4 h2 = h4[e2.x*32 + l];
    float4 h3 = h4[e3.x*32 + l];
    float w0 = __int_as_float(e0.y), w1 = __int_as_float(e1.y);
    float w2 = __int_as_float(e2.y), w3 = __int_as_float(e3.y);
    acc.x += w0*h0.x + w1*h1.x + w2*h2.x + w3*h3.x;
    acc.y += w0*h0.y + w1*h1.y + w2*h2.y + w3*h3.y;
    acc.z += w0*h0.z + w1*h1.z + w2*h2.z + w3*h3.z;
    acc.w += w0*h0.w + w1*h1.w + w2*h2.w + w3*h3.w;
  }
  for (; j < c; j++){
    int2 e = csr[start + j];
    float wgt = __int_as_float(e.y);
    float4 hv = h4[e.x*32 + l];
    acc.x += wgt*hv.x; acc.y += wgt*hv.y; acc.z += wgt*hv.z; acc.w += wgt*hv.w;
  }
  float di = dinv[node], dd = di*di;
  float4 hs = h4[node*32 + l];
  float4 bb = bias4[l];
  float4 v;
  v.x = fmaxf(acc.x + hs.x*dd + bb.x, 0.f);
  v.y = fmaxf(acc.y + hs.y*dd + bb.y, 0.f);
  v.z = fmaxf(acc.z + hs.z*dd + bb.z, 0.f);
  v.w = fmaxf(acc.w + hs.w*dd + bb.w, 0.f);
  out4[node*32 + l] = v;
  float4 wp = Wp4[l];
  float contrib = v.x*wp.x + v.y*wp.y + v.z*wp.z + v.w*wp.w;
  #pragma unroll
  for (int off = 16; off; off >>= 1) contrib += __shfl_down(contrib, off, 32);
  if (l == 0) hp[node] = contrib;
}

// Per-graph mega: score (4-batched CSR loads) -> hybrid shfl/LDS bitonic
// top-k -> pooled rows + fused readout -> relabel + next topology.
// zstore: L1 stores readout partials (no prior zeroing needed).
// Last level: fused readout finalize + MLP + log_softmax.
__global__ __launch_bounds__(512) void k_mega(
    const float4* __restrict__ gout4, const float* __restrict__ hp_part,
    int l1flag, const float* __restrict__ hp,
    int2* __restrict__ csr, int* __restrict__ rowptr, int* __restrict__ cnt,
    float* __restrict__ dinv, const float* __restrict__ bp,
    int2* __restrict__ edges, float4* __restrict__ xpool4,
    float* __restrict__ z, int nper, int lastlev,
    const float* __restrict__ L1W, const float* __restrict__ L1b,
    const float* __restrict__ L2W, const float* __restrict__ L2b,
    float* __restrict__ out){
  __shared__ float sv[512];
  __shared__ int   si[512];
  __shared__ float hpl[512];
  __shared__ int   map[512];
  __shared__ int   sb[512];
  __shared__ int   cur[256];
  __shared__ float dl[256];
  __shared__ float4 pmx[16][32];
  __shared__ float4 psm[16][32];
  __shared__ float zr[256];
  __shared__ float h1[128];
  __shared__ float h2[64];
  __shared__ float red[2];
  int g = (blockIdx.x & 7)*8 + (blockIdx.x >> 3);
  int t = threadIdx.x;
  int k = nper >> 1;
  int gbase = g*nper, ebase = g*EPG, gb2 = g*k;
  bool act = t < nper;
  if (act){
    int node = gbase + t;
    hpl[t] = l1flag ? (hp_part[node] + hp_part[32768 + node] +
                       hp_part[65536 + node] + hp_part[98304 + node])
                    : hp[node];
  }
  __syncthreads();
  float v = 0.f; int idx = t;
  if (act){
    int start = rowptr[gbase + t], c = cnt[gbase + t];
    float a = 0.f;
    int j = 0;
    for (; j + 4 <= c; j += 4){
      int2 e0 = csr[start+j],   e1 = csr[start+j+1];
      int2 e2 = csr[start+j+2], e3 = csr[start+j+3];
      a += __int_as_float(e0.y)*hpl[e0.x - gbase]
         + __int_as_float(e1.y)*hpl[e1.x - gbase]
         + __int_as_float(e2.y)*hpl[e2.x - gbase]
         + __int_as_float(e3.y)*hpl[e3.x - gbase];
    }
    for (; j < c; j++){
      int2 e = csr[start + j];
      a += __int_as_float(e.y)*hpl[e.x - gbase];
    }
    float di = dinv[gbase + t];
    v = tanhf(a + hpl[t]*di*di + bp[0]);
  }
  for (int kk = 2; kk <= nper; kk <<= 1){
    for (int jj = kk >> 1; jj > 0; jj >>= 1){
      if (jj >= 64){
        if (act){ sv[t] = v; si[t] = idx; }
        __syncthreads();
        if (act){
          int p = t ^ jj;
          float pv = sv[p]; int pi = si[p];
          bool amLower = (t & jj) == 0;
          bool dirDesc = (t & kk) == 0;
          bool betterMine = (v > pv) || (v == pv && idx < pi);
          if ((amLower == dirDesc) != betterMine){ v = pv; idx = pi; }
        }
        __syncthreads();
      } else if (act){
        float pv = __shfl_xor(v, jj);
        int   pi = __shfl_xor(idx, jj);
        bool amLower = (t & jj) == 0;
        bool dirDesc = (t & kk) == 0;
        bool betterMine = (v > pv) || (v == pv && idx < pi);
        if ((amLower == dirDesc) != betterMine){ v = pv; idx = pi; }
      }
    }
  }
  if (act){ sv[t] = v; si[t] = idx; }
  __syncthreads();
  int l = t & 31, j0 = t >> 5;
  float4 mx = make_float4(-INFINITY,-INFINITY,-INFINITY,-INFINITY);
  float4 sm = make_float4(0.f,0.f,0.f,0.f);
  for (int j = j0; j < k; j += 16){
    float val = sv[j]; int row = si[j];
    float4 hv = gout4[(gbase + row)*32 + l];
    float4 o = make_float4(hv.x*val, hv.y*val, hv.z*val, hv.w*val);
    if (!lastlev) xpool4[(gb2 + j)*32 + l] = o;
    mx.x = fmaxf(mx.x, o.x); mx.y = fmaxf(mx.y, o.y);
    mx.z = fmaxf(mx.z, o.z); mx.w = fmaxf(mx.w, o.w);
    sm.x += o.x; sm.y += o.y; sm.z += o.z; sm.w += o.w;
  }
  pmx[j0][l] = mx; psm[j0][l] = sm;
  __syncthreads();
  if (t < 32){
    float4 M = pmx[0][t], S = psm[0][t];
    #pragma unroll
    for (int q = 1; q < 16; q++){
      float4 m2 = pmx[q][t], s2 = psm[q][t];
      M.x = fmaxf(M.x, m2.x); M.y = fmaxf(M.y, m2.y);
      M.z = fmaxf(M.z, m2.z); M.w = fmaxf(M.w, m2.w);
      S.x += s2.x; S.y += s2.y; S.z += s2.z; S.w += s2.w;
    }
    float ki = 1.f/(float)k;
    float* zp = z + g*256;
    if (l1flag){                           // first level: store (no prior zero)
      zp[t*4+0] = M.x; zp[t*4+1] = M.y; zp[t*4+2] = M.z; zp[t*4+3] = M.w;
      zp[128+t*4+0] = S.x*ki; zp[128+t*4+1] = S.y*ki;
      zp[128+t*4+2] = S.z*ki; zp[128+t*4+3] = S.w*ki;
    } else if (!lastlev){
      zp[t*4+0] += M.x; zp[t*4+1] += M.y; zp[t*4+2] += M.z; zp[t*4+3] += M.w;
      zp[128+t*4+0] += S.x*ki; zp[128+t*4+1] += S.y*ki;
      zp[128+t*4+2] += S.z*ki; zp[128+t*4+3] += S.w*ki;
    } else {
      zr[t*4+0] = zp[t*4+0] + M.x; zr[t*4+1] = zp[t*4+1] + M.y;
      zr[t*4+2] = zp[t*4+2] + M.z; zr[t*4+3] = zp[t*4+3] + M.w;
      zr[128+t*4+0] = zp[128+t*4+0] + S.x*ki;
      zr[128+t*4+1] = zp[128+t*4+1] + S.y*ki;
      zr[128+t*4+2] = zp[128+t*4+2] + S.z*ki;
      zr[128+t*4+3] = zp[128+t*4+3] + S.w*ki;
    }
  }
  if (lastlev){
    __syncthreads();
    if (t < 128){
      float a = L1b[t];
      for (int i = 0; i < 256; i++) a += zr[i]*L1W[i*128 + t];
      h1[t] = fmaxf(a, 0.f);
    }
    __syncthreads();
    if (t < 64){
      float a = L2b[t];
      for (int i = 0; i < 128; i++) a += h1[i]*L2W[i*64 + t];
      h2[t] = fmaxf(a, 0.f);
    }
    __syncthreads();
    if (t == 0){
      float mxv = -INFINITY;
      for (int i = 0; i < 64; i++) mxv = fmaxf(mxv, h2[i]);
      float s = 0.f;
      for (int i = 0; i < 64; i++) s += expf(h2[i] - mxv);
      red[0] = mxv; red[1] = logf(s);
    }
    __syncthreads();
    if (t < 64) out[g*64 + t] = h2[t] - red[0] - red[1];
    return;
  }
  if (act) map[t] = -1;
  if (t < k) sb[t] = 0;
  __syncthreads();
  if (t < k) map[si[t]] = t;
  __syncthreads();
  int2 ebuf[EIT];
  #pragma unroll
  for (int it = 0; it < EIT; it++){
    int i = ebase + it*512 + t;
    int2 e = edges[i];
    int2 ne = make_int2(-1, 0);
    if (e.x >= 0){
      int ns = map[e.x - gbase], nd = map[e.y - gbase];
      if (ns >= 0 && nd >= 0){
        ne = make_int2(gb2 + ns, gb2 + nd);
        atomicAdd(&sb[nd], 1);
      }
    }
    ebuf[it] = ne;
    edges[i] = ne;
  }
  __syncthreads();
  int vdeg = (t < k) ? sb[t] : 0;
  for (int off = 1; off < k; off <<= 1){
    int add = (t >= off && t < k) ? sb[t-off] : 0;
    __syncthreads();
    if (t < k) sb[t] += add;
    __syncthreads();
  }
  if (t < k){
    int excl = sb[t] - vdeg;
    rowptr[gb2 + t] = ebase + excl;
    cnt[gb2 + t] = vdeg;
    cur[t] = excl;
    float dv = rsqrtf((float)vdeg + 1.f);
    dl[t] = dv;
    dinv[gb2 + t] = dv;
  }
  __syncthreads();
  #pragma unroll
  for (int it = 0; it < EIT; it++){
    int2 e = ebuf[it];
    if (e.x >= 0){
      int sl = e.x - gb2, dc = e.y - gb2;
      int pos = atomicAdd(&cur[dc], 1);
      csr[ebase + pos] = make_int2(e.x, __float_as_int(dl[sl]*dl[dc]));
    }
  }
}

extern "C" void kernel_launch(void* const* d_in, const int* in_sizes, int n_in,
                              void* d_out, int out_size, void* d_ws, size_t ws_size,
                              hipStream_t stream){
  (void)in_sizes; (void)n_in; (void)out_size; (void)ws_size;
  const float* x0  = (const float*)d_in[0];
  const int*   s0  = (const int*)  d_in[1];
  const int*   d0  = (const int*)  d_in[2];
  const float* W1  = (const float*)d_in[3];  const float* b1 = (const float*)d_in[4];
  const float* W2  = (const float*)d_in[5];  const float* b2 = (const float*)d_in[6];
  const float* W3  = (const float*)d_in[7];  const float* b3 = (const float*)d_in[8];
  const float* Wp  = (const float*)d_in[9];  const float* bp = (const float*)d_in[10];
  const float* L1W = (const float*)d_in[11]; const float* L1b = (const float*)d_in[12];
  const float* L2W = (const float*)d_in[13]; const float* L2b = (const float*)d_in[14];
  float* out = (float*)d_out;

  // workspace layout (elements). xp buffers overlay dead tails of h/gout.
  float* w = (float*)d_ws;
  float* h     = w; w += 32768*HID;          // L2/L3 XW scratch
  float* gout  = w; w += 32768*HID;
  float* xpA   = h    + 16384*HID;           // level-1 pool out — h tail
  float* xpB   = gout + 16384*HID;           // level-2 pool out — gout tail
  float* xpC   = xpA;                        // level-3 pool out — xpA dead by then
  float* dinvv = w; w += 32768;
  float* hp    = w; w += 32768;
  float* hppt  = w; w += 4*32768;            // L1 hp quarter-partials
  float* z     = w; w += BGR*256;
  int* cnt     = (int*)w; w += 32768;
  int* rowptr  = (int*)w; w += 32768;
  int2* edges  = (int2*)w; w += 2*E_TOT;
  int2* csr    = (int2*)w; w += 2*E_TOT;

  k_topo0<<<BGR, 512, 0, stream>>>(s0, d0, edges, cnt, rowptr, dinvv, csr);

  // level 1: 512 -> 256 (fused gemm+gather in LDS, 2 blocks/CU)
  k_l1_fused<<<512, 512, 65536, stream>>>(x0, W1, csr, rowptr, cnt, dinvv,
                                          b1, Wp, (float4*)gout, hppt);
  k_mega<<<BGR, 512, 0, stream>>>((const float4*)gout, hppt, 1, hp, csr, rowptr,
                                  cnt, dinvv, bp, edges, (float4*)xpA, z, 512, 0,
                                  L1W, L1b, L2W, L2b, out);
  // level 2: 256 -> 128
  k_gemm16<<<16384/16, HID, 0, stream>>>(xpA, W2, h, 256);
  k_gcn_gather<<<16384/8, 256, 0, stream>>>((const float4*)h, csr, rowptr, cnt,
                                            dinvv, (const float4*)b2,
                                            (const float4*)Wp, (float4*)gout,
                                            hp, 256);
  k_mega<<<BGR, 512, 0, stream>>>((const float4*)gout, hppt, 0, hp, csr, rowptr,
                                  cnt, dinvv, bp, edges, (float4*)xpB, z, 256, 0,
                                  L1W, L1b, L2W, L2b, out);
  // level 3: 128 -> 64 (+ fused readout/MLP/log_softmax)
  k_gemm16<<<8192/16, HID, 0, stream>>>(xpB, W3, h, 128);
  k_gcn_gather<<<8192/8, 256, 0, stream>>>((const float4*)h, csr, rowptr, cnt,
                                           dinvv, (const float4*)b3,
                                           (const float4*)Wp, (float4*)gout,
                                           hp, 128);
  k_mega<<<BGR, 512, 0, stream>>>((const float4*)gout, hppt, 0, hp, csr, rowptr,
                                  cnt, dinvv, bp, edges, (float4*)xpC, z, 128, 1,
                                  L1W, L1b, L2W, L2b, out);
}